// Round 9
// baseline (201.174 us; speedup 1.0000x reference)
//
#include <hip/hip_runtime.h>
#include <hip/hip_bf16.h>
#include <math.h>

typedef __attribute__((ext_vector_type(8))) short bf16x8;
typedef __attribute__((ext_vector_type(8))) unsigned short u16x8;
typedef __attribute__((ext_vector_type(4))) float f32x4;
typedef __attribute__((ext_vector_type(16))) float f32x16;

__device__ __forceinline__ unsigned short f2bf(float f) {
  unsigned u = __float_as_uint(f);
  return (unsigned short)((u + 0x7FFFu + ((u >> 16) & 1u)) >> 16);
}
__device__ __forceinline__ float bf2f(unsigned short h) {
  return __uint_as_float(((unsigned)h) << 16);
}
// fp32x8 -> bf16 hi/lo split via packed cvt (compiler emits v_cvt_pk_bf16_f32)
__device__ __forceinline__ void cvt8pk(const float4& a, const float4& b,
                                       u16x8& h, u16x8& l) {
  float f[8] = {a.x, a.y, a.z, a.w, b.x, b.y, b.z, b.w};
  unsigned* hp = (unsigned*)&h;
  unsigned* lp = (unsigned*)&l;
#pragma unroll
  for (int i = 0; i < 4; ++i) {
    __hip_bfloat162 hb = __float22bfloat162_rn(make_float2(f[2*i], f[2*i+1]));
    unsigned hv = *(unsigned*)&hb;
    hp[i] = hv;
    float r0 = f[2*i]     - __uint_as_float(hv << 16);
    float r1 = f[2*i + 1] - __uint_as_float(hv & 0xFFFF0000u);
    __hip_bfloat162 lb = __float22bfloat162_rn(make_float2(r0, r1));
    lp[i] = *(unsigned*)&lb;
  }
}
__device__ __forceinline__ void cvt8pk2(const f32x4& a, const f32x4& b,
                                        u16x8& h, u16x8& l) {
  float f[8] = {a[0], a[1], a[2], a[3], b[0], b[1], b[2], b[3]};
  unsigned* hp = (unsigned*)&h;
  unsigned* lp = (unsigned*)&l;
#pragma unroll
  for (int i = 0; i < 4; ++i) {
    __hip_bfloat162 hb = __float22bfloat162_rn(make_float2(f[2*i], f[2*i+1]));
    unsigned hv = *(unsigned*)&hb;
    hp[i] = hv;
    float r0 = f[2*i]     - __uint_as_float(hv << 16);
    float r1 = f[2*i + 1] - __uint_as_float(hv & 0xFFFF0000u);
    __hip_bfloat162 lb = __float22bfloat162_rn(make_float2(r0, r1));
    lp[i] = *(unsigned*)&lb;
  }
}
__device__ __forceinline__ void cvt8b(const float4& a, const float4& b,
                                      bf16x8& h, bf16x8& l) {
  u16x8 hh, ll;
  cvt8pk(a, b, hh, ll);
  h = *(bf16x8*)&hh;
  l = *(bf16x8*)&ll;
}

#define GLD16(g, l) __builtin_amdgcn_global_load_lds( \
    (const __attribute__((address_space(1))) void*)(g), \
    (__attribute__((address_space(3))) void*)(l), 16, 0, 0)

#define MFMA32(a, b, c) __builtin_amdgcn_mfma_f32_32x32x16_bf16(a, b, c, 0, 0, 0)

// ---------------------------------------------------------------------------
// K0 (merged): blocks 0-15: split/transpose Wp -> th1/tl1 [kt16][ks8][col128][e8]
//              blocks 16-31: split Wflat -> th2/tl2 [kt2][ks8][col512][e8]
//              blocks 32-95: Gram M[a][b] = Wf[a]·Wf[b]
// ---------------------------------------------------------------------------
__global__ __launch_bounds__(256) void caps_prep_all(
    const float* __restrict__ Wp, const float* __restrict__ W,
    unsigned short* __restrict__ th1, unsigned short* __restrict__ tl1,
    unsigned short* __restrict__ th2, unsigned short* __restrict__ tl2,
    float* __restrict__ M)
{
  __shared__ float tile[64][128];
  const int t = threadIdx.x, b = blockIdx.x;
  if (b < 16) {
    const float* src = Wp + (size_t)b * 64 * 128;
#pragma unroll
    for (int i = 0; i < 8; ++i) {
      int j = t + i * 256;
      int kk = j >> 5, q = j & 31;
      *(float4*)&tile[kk][q * 4] = *(const float4*)(src + kk * 128 + q * 4);
    }
    __syncthreads();
    const int col = t >> 1, kg0 = (t & 1) * 4;
    unsigned short hi[32], lo[32];
#pragma unroll
    for (int kk = 0; kk < 32; ++kk) {
      float v = tile[kg0 * 8 + kk][col];
      unsigned short h = f2bf(v);
      hi[kk] = h;
      lo[kk] = f2bf(v - bf2f(h));
    }
#pragma unroll
    for (int i = 0; i < 4; ++i) {
      size_t off = (size_t)b * 8192 + (size_t)(kg0 + i) * 1024 + (size_t)col * 8;
      u16x8 vh, vl;
#pragma unroll
      for (int e = 0; e < 8; ++e) { vh[e] = hi[i * 8 + e]; vl[e] = lo[i * 8 + e]; }
      *(u16x8*)(th1 + off) = vh;
      *(u16x8*)(tl1 + off) = vl;
    }
  } else if (b < 32) {
    int tt = (b - 16) * 256 + t;
#pragma unroll
    for (int h = 0; h < 2; ++h) {
      int c = tt + h * 4096;
      int kt = c >> 12, rem = c & 4095;
      int kg = rem >> 9, col = rem & 511;
      int kbase = kt * 64 + kg * 8;
      u16x8 vh, vl;
#pragma unroll
      for (int e = 0; e < 8; ++e) {
        float v = W[(size_t)(kbase + e) * 512 + col];
        unsigned short hh = f2bf(v);
        vh[e] = hh;
        vl[e] = f2bf(v - bf2f(hh));
      }
      size_t off = ((size_t)(kt * 8 + kg) * 512 + col) * 8;
      *(u16x8*)(th2 + off) = vh;
      *(u16x8*)(tl2 + off) = vl;
    }
  } else {
    int bb = b - 32;
    int a = (bb >> 3) * 16 + (t >> 4);
    int c = (bb & 7) * 16 + (t & 15);
    const float* wa = W + (size_t)a * 512;
    const float* wb = W + (size_t)c * 512;
    float acc = 0.f;
#pragma unroll 4
    for (int o = 0; o < 512; o += 4) {
      float4 xx = *(const float4*)(wa + o);
      float4 yy = *(const float4*)(wb + o);
      acc += xx.x * yy.x + xx.y * yy.y + xx.z * yy.z + xx.w * yy.w;
    }
    M[a * 128 + c] = acc;
  }
}

// ---------------------------------------------------------------------------
// K1: p = squash(x @ Wp + bp), split-bf16 via 32x32x16 MFMA.
// Same as round 8 EXCEPT: x loaded nontemporally (streaming operand must not
// evict the 1 MB re-read B tiles from L2 — B-eviction theory).
// ---------------------------------------------------------------------------
#define K1BUF 20480   // shorts per buffer (40 KB)

__global__ __launch_bounds__(256) void caps_primary(
    const float* __restrict__ x, const unsigned short* __restrict__ bth,
    const unsigned short* __restrict__ btl, const float* __restrict__ bp,
    float* __restrict__ p_out)
{
  __shared__ unsigned short lds[2 * K1BUF];   // 80 KB
  const int tid  = threadIdx.x;
  const int lane = tid & 63;
  const int wn   = tid >> 6;       // 0..3 -> cols wn*32..+31
  const int lc   = lane & 31;
  const int hi   = lane >> 5;
  const int row0 = blockIdx.x * 32;

  const int rowA = tid & 31;       // A staging: (row=rowA, ks=kgA)
  const int kgA  = tid >> 5;       // 0..7
  const float* xrow = x + (size_t)(row0 + rowA) * 1024 + kgA * 8;

  f32x16 acc;
#pragma unroll
  for (int j = 0; j < 16; ++j) acc[j] = 0.f;

  f32x4 a0, a1;

#define A_LOAD(kt) do { const float* xp_ = xrow + (kt) * 64; \
    a0 = __builtin_nontemporal_load((const f32x4*)(xp_)); \
    a1 = __builtin_nontemporal_load((const f32x4*)(xp_ + 4)); } while (0)

#define B_ISSUE(kt, bufi) do { \
    unsigned short* Bh_ = lds + (bufi) * K1BUF + 4096; \
    unsigned short* Bl_ = lds + (bufi) * K1BUF + 12288; \
    const unsigned short* gh_ = bth + ((size_t)(kt) * 1024 + tid) * 8; \
    const unsigned short* gl_ = btl + ((size_t)(kt) * 1024 + tid) * 8; \
    _Pragma("unroll") for (int c_ = 0; c_ < 4; ++c_) { \
      GLD16(gh_ + c_ * 2048, Bh_ + (c_ * 256 + tid) * 8); \
      GLD16(gl_ + c_ * 2048, Bl_ + (c_ * 256 + tid) * 8); \
    } } while (0)

#define A_WRITE(bufi) do { u16x8 h_, l_; cvt8pk2(a0, a1, h_, l_); \
    unsigned short* A_ = lds + (bufi) * K1BUF; \
    *(u16x8*)(A_ + (kgA * 32 + rowA) * 8) = h_; \
    *(u16x8*)(A_ + 2048 + (kgA * 32 + rowA) * 8) = l_; } while (0)

#define COMPUTE(bufi) do { \
    const unsigned short* F = lds + (bufi) * K1BUF; \
    _Pragma("unroll") \
    for (int kk = 0; kk < 4; ++kk) { \
      const int ks = kk * 2 + hi; \
      bf16x8 ah  = *(const bf16x8*)(F + (ks * 32 + lc) * 8); \
      bf16x8 al  = *(const bf16x8*)(F + 2048 + (ks * 32 + lc) * 8); \
      bf16x8 bh  = *(const bf16x8*)(F + 4096  + (ks * 128 + wn * 32 + lc) * 8); \
      bf16x8 blo = *(const bf16x8*)(F + 12288 + (ks * 128 + wn * 32 + lc) * 8); \
      acc = MFMA32(ah, bh,  acc); \
      acc = MFMA32(ah, blo, acc); \
      acc = MFMA32(al, bh,  acc); \
    } } while (0)

  // prologue
  A_LOAD(0);
  B_ISSUE(0, 0);
  A_WRITE(0);
  __syncthreads();

#pragma unroll 2
  for (int kt = 0; kt < 16; ++kt) {
    const int cur = kt & 1;
    if (kt < 15) {
      A_LOAD(kt + 1);           // global->reg (A), issued first
      B_ISSUE(kt + 1, cur ^ 1); // global->LDS async (B)
    }
    COMPUTE(cur);
    if (kt < 15) A_WRITE(cur ^ 1);
    __syncthreads();
  }
#undef A_LOAD
#undef B_ISSUE
#undef A_WRITE
#undef COMPUTE

  // epilogue: bias + per-capsule squash.
  // C/D 32x32: col = wn*32 + lc, row = (r&3) + 8*(r>>2) + 4*hi.
  const int col = wn * 32 + lc;
  const float bpv = bp[col];
#pragma unroll
  for (int r = 0; r < 16; ++r) {
    const int row = (r & 3) + 8 * (r >> 2) + 4 * hi;
    float val = acc[r] + bpv;
    float sq = val * val;
    sq += __shfl_xor(sq, 1); sq += __shfl_xor(sq, 2);
    sq += __shfl_xor(sq, 4); sq += __shfl_xor(sq, 8);
    float sc = (sq / (1.f + sq)) / sqrtf(sq + 1e-8f);
    p_out[(size_t)(row0 + row) * 128 + col] = val * sc;
  }
}

// ---------------------------------------------------------------------------
// K2: Gram-based routing, REWRITTEN.
// 512 blocks x 256 thr, 32 rows/block (2 blocks/CU). Thread (n = tid&7,
// r = tid>>3) computes G[r][n][m] for all m with STATIC arithmetic indexing
// (no device tables). M read directly from L2 (64 lanes share 8 addresses).
// Then 32 threads route their row; q = cs*p written from LDS.
// ---------------------------------------------------------------------------
__global__ __launch_bounds__(256) void caps_route_g(
    const float* __restrict__ p_in, const float* __restrict__ Mg,
    float* __restrict__ qout)
{
  __shared__ float p_lds[32 * 132];   // 16.5 KB, row stride 132 (f4-aligned)
  __shared__ float G_lds[32 * 65];    // 8.1 KB, stride 65 (odd -> conflict-free)
  __shared__ float cs_lds[32 * 9];
  const int tid  = threadIdx.x;
  const int row0 = blockIdx.x * 32;

  // stage p rows (coalesced float4)
#pragma unroll
  for (int i = 0; i < 4; ++i) {
    int j = tid + i * 256;
    int r = j >> 5, c4 = j & 31;
    *(f32x4*)&p_lds[r * 132 + c4 * 4] =
        *(const f32x4*)(p_in + (size_t)(row0 + r) * 128 + c4 * 4);
  }
  __syncthreads();

  // G phase: fully static (n fixed per thread, m unrolled)
  {
    const int n = tid & 7;
    const int r = tid >> 3;
    float pn[16];
#pragma unroll
    for (int j = 0; j < 16; ++j) pn[j] = p_lds[r * 132 + n * 16 + j];
    const float* Mbase = Mg + (size_t)n * 16 * 128;
#pragma unroll
    for (int m = 0; m < 8; ++m) {
      float pm[16];
#pragma unroll
      for (int j = 0; j < 16; ++j) pm[j] = p_lds[r * 132 + m * 16 + j];
      float acc = 0.f;
#pragma unroll
      for (int ii = 0; ii < 16; ++ii) {
        const float* Mr = Mbase + ii * 128 + m * 16;
        float t = 0.f;
#pragma unroll
        for (int j4 = 0; j4 < 4; ++j4) {
          f32x4 mv = *(const f32x4*)(Mr + j4 * 4);
          t = fmaf(mv[0], pm[j4 * 4 + 0], t);
          t = fmaf(mv[1], pm[j4 * 4 + 1], t);
          t = fmaf(mv[2], pm[j4 * 4 + 2], t);
          t = fmaf(mv[3], pm[j4 * 4 + 3], t);
        }
        acc = fmaf(pn[ii], t, acc);
      }
      G_lds[r * 65 + n * 8 + m] = acc;
    }
  }
  __syncthreads();

  // routing phase: thread tr < 32 owns row tr
  if (tid < 32) {
    float Gf[64];
#pragma unroll
    for (int j = 0; j < 64; ++j) Gf[j] = G_lds[tid * 65 + j];
    float bb[8] = {0.f, 0.f, 0.f, 0.f, 0.f, 0.f, 0.f, 0.f};
    float cs[8];
#pragma unroll
    for (int it = 0; it < 3; ++it) {
      float mx = bb[0];
#pragma unroll
      for (int n = 1; n < 8; ++n) mx = fmaxf(mx, bb[n]);
      float e[8], Z = 0.f;
#pragma unroll
      for (int n = 0; n < 8; ++n) { e[n] = expf(bb[n] - mx); Z += e[n]; }
      float inv = 1.f / Z;
      float c[8];
#pragma unroll
      for (int n = 0; n < 8; ++n) c[n] = e[n] * inv;
      float t[8] = {0.f, 0.f, 0.f, 0.f, 0.f, 0.f, 0.f, 0.f};
#pragma unroll
      for (int n = 0; n < 8; ++n)
#pragma unroll
        for (int m = 0; m < 8; ++m)
          t[n] = fmaf(Gf[n * 8 + m], c[m], t[n]);
      float ss = 0.f;
#pragma unroll
      for (int n = 0; n < 8; ++n) ss = fmaf(c[n], t[n], ss);
      float scale = (ss / (1.f + ss)) / sqrtf(ss + 1e-8f);
      if (it < 2) {
#pragma unroll
        for (int n = 0; n < 8; ++n) bb[n] += scale * t[n];
      } else {
#pragma unroll
        for (int n = 0; n < 8; ++n) cs[n] = scale * c[n];
      }
    }
#pragma unroll
    for (int n = 0; n < 8; ++n) cs_lds[tid * 9 + n] = cs[n];
  }
  __syncthreads();

  // q = cs * p, from LDS, coalesced write (in-place over p is safe)
#pragma unroll
  for (int i = 0; i < 4; ++i) {
    int j = tid + i * 256;
    int r = j >> 5, c4 = j & 31;
    f32x4 pv = *(const f32x4*)&p_lds[r * 132 + c4 * 4];
    float csv = cs_lds[r * 9 + (c4 >> 2)];
    f32x4 qv = {pv[0] * csv, pv[1] * csv, pv[2] * csv, pv[3] * csv};
    *(f32x4*)(qout + (size_t)(row0 + r) * 128 + c4 * 4) = qv;
  }
}

// ---------------------------------------------------------------------------
// K3: v = q @ Wflat  [16384,128]x[128,512] split-bf16 via 32x32x16 MFMA.
// (unchanged, verified)
// ---------------------------------------------------------------------------
__global__ __launch_bounds__(512) void caps_vout(
    const float* __restrict__ q, const unsigned short* __restrict__ bth,
    const unsigned short* __restrict__ btl, float* __restrict__ out)
{
  __shared__ unsigned short Bsh[32768];   // hi @0, lo @16384 (ushorts)
  const int tid  = threadIdx.x;
  const int lane = tid & 63;
  const int w    = tid >> 6;
  const int wm   = w >> 2;         // 0..1 -> rows wm*32..+31
  const int wn   = w & 3;          // 0..3 -> cols wn*32..+31
  const int lc   = lane & 31;
  const int hi   = lane >> 5;
  const int row0 = blockIdx.x * 64;
  const int col0 = blockIdx.y * 128;

#pragma unroll
  for (int i = 0; i < 4; ++i) {
    int idx = tid + i * 512;               // 2048 chunks
    int kt = idx >> 10, kg = (idx >> 7) & 7, col = idx & 127;
    size_t g = ((size_t)(kt * 8 + kg) * 512 + col0 + col) * 8;
    *(u16x8*)&Bsh[idx * 8] = *(const u16x8*)(bth + g);
    *(u16x8*)&Bsh[16384 + idx * 8] = *(const u16x8*)(btl + g);
  }
  __syncthreads();

  const float* qp = q + (size_t)(row0 + wm * 32 + lc) * 128;

  f32x16 acc;
#pragma unroll
  for (int j = 0; j < 16; ++j) acc[j] = 0.f;

#pragma unroll
  for (int kt = 0; kt < 2; ++kt) {
#pragma unroll
    for (int kk = 0; kk < 4; ++kk) {
      const float* qk = qp + kt * 64 + kk * 16 + hi * 8;
      float4 a0 = *(const float4*)(qk);
      float4 a1 = *(const float4*)(qk + 4);
      bf16x8 ah, al;
      cvt8b(a0, a1, ah, al);
      const int ks = kk * 2 + hi;
      const int fi = ((kt * 8 + ks) * 128 + wn * 32 + lc) * 8;
      bf16x8 bh  = *(const bf16x8*)&Bsh[fi];
      bf16x8 blo = *(const bf16x8*)&Bsh[16384 + fi];
      acc = MFMA32(ah, bh,  acc);
      acc = MFMA32(ah, blo, acc);
      acc = MFMA32(al, bh,  acc);
    }
  }

#pragma unroll
  for (int r = 0; r < 16; ++r) {
    const int row = (r & 3) + 8 * (r >> 2) + 4 * hi;
    out[(size_t)(row0 + wm * 32 + row) * 512 + col0 + wn * 32 + lc] = acc[r];
  }
}

extern "C" void kernel_launch(void* const* d_in, const int* in_sizes, int n_in,
                              void* d_out, int out_size, void* d_ws, size_t ws_size,
                              hipStream_t stream) {
  (void)in_sizes; (void)n_in; (void)out_size; (void)ws_size;
  const float* x  = (const float*)d_in[0];
  const float* Wp = (const float*)d_in[1];
  const float* bp = (const float*)d_in[2];
  const float* W  = (const float*)d_in[3];
  // d_in[4] = n_routing (fixed = 3)
  char* ws = (char*)d_ws;
  float* p_ws = (float*)ws;                                   // 8 MB (p, then q in-place)
  unsigned short* th1 = (unsigned short*)(ws + 8388608);      // 256 KB
  unsigned short* tl1 = (unsigned short*)(ws + 8650752);      // 256 KB
  unsigned short* th2 = (unsigned short*)(ws + 8912896);      // 128 KB
  unsigned short* tl2 = (unsigned short*)(ws + 9043968);      // 128 KB
  float* Mws = (float*)(ws + 9175040);                        // 64 KB
  float* outp = (float*)d_out;

  caps_prep_all<<<96, 256, 0, stream>>>(Wp, W, th1, tl1, th2, tl2, Mws);
  caps_primary<<<512, 256, 0, stream>>>(x, th1, tl1, bp, p_ws);
  caps_route_g<<<512, 256, 0, stream>>>(p_ws, Mws, p_ws);
  caps_vout<<<dim3(256, 4), 512, 0, stream>>>(p_ws, th2, tl2, outp);
}

// Round 10
// 131.151 us; speedup vs baseline: 1.5339x; 1.5339x over previous
//
#include <hip/hip_runtime.h>
#include <hip/hip_bf16.h>
#include <math.h>

typedef __attribute__((ext_vector_type(8))) short bf16x8;
typedef __attribute__((ext_vector_type(8))) unsigned short u16x8;
typedef __attribute__((ext_vector_type(4))) float f32x4;
typedef __attribute__((ext_vector_type(16))) float f32x16;

__device__ __forceinline__ unsigned short f2bf(float f) {
  unsigned u = __float_as_uint(f);
  return (unsigned short)((u + 0x7FFFu + ((u >> 16) & 1u)) >> 16);
}
__device__ __forceinline__ float bf2f(unsigned short h) {
  return __uint_as_float(((unsigned)h) << 16);
}
// fp32x8 -> bf16 hi/lo split via packed cvt (compiler emits v_cvt_pk_bf16_f32)
__device__ __forceinline__ void cvt8pk(const float4& a, const float4& b,
                                       u16x8& h, u16x8& l) {
  float f[8] = {a.x, a.y, a.z, a.w, b.x, b.y, b.z, b.w};
  unsigned* hp = (unsigned*)&h;
  unsigned* lp = (unsigned*)&l;
#pragma unroll
  for (int i = 0; i < 4; ++i) {
    __hip_bfloat162 hb = __float22bfloat162_rn(make_float2(f[2*i], f[2*i+1]));
    unsigned hv = *(unsigned*)&hb;
    hp[i] = hv;
    float r0 = f[2*i]     - __uint_as_float(hv << 16);
    float r1 = f[2*i + 1] - __uint_as_float(hv & 0xFFFF0000u);
    __hip_bfloat162 lb = __float22bfloat162_rn(make_float2(r0, r1));
    lp[i] = *(unsigned*)&lb;
  }
}
__device__ __forceinline__ void cvt8b(const float4& a, const float4& b,
                                      bf16x8& h, bf16x8& l) {
  u16x8 hh, ll;
  cvt8pk(a, b, hh, ll);
  h = *(bf16x8*)&hh;
  l = *(bf16x8*)&ll;
}

#define GLD16(g, l) __builtin_amdgcn_global_load_lds( \
    (const __attribute__((address_space(1))) void*)(g), \
    (__attribute__((address_space(3))) void*)(l), 16, 0, 0)

#define MFMA32(a, b, c) __builtin_amdgcn_mfma_f32_32x32x16_bf16(a, b, c, 0, 0, 0)

__device__ __forceinline__ constexpr int gidx(int a, int b) {
  int m = a < b ? a : b, n = a < b ? b : a;
  return m * 8 - (m * (m - 1)) / 2 + (n - m);
}

// ---------------------------------------------------------------------------
// K0 (merged): blocks 0-15: split/transpose Wp -> th1/tl1 [kt16][ks8][col128][e8]
//              blocks 16-31: split Wflat -> th2/tl2 [kt2][ks8][col512][e8]
//              blocks 32-95: Gram M[a][b] = Wf[a]·Wf[b]
// ---------------------------------------------------------------------------
__global__ __launch_bounds__(256) void caps_prep_all(
    const float* __restrict__ Wp, const float* __restrict__ W,
    unsigned short* __restrict__ th1, unsigned short* __restrict__ tl1,
    unsigned short* __restrict__ th2, unsigned short* __restrict__ tl2,
    float* __restrict__ M)
{
  __shared__ float tile[64][128];
  const int t = threadIdx.x, b = blockIdx.x;
  if (b < 16) {
    const float* src = Wp + (size_t)b * 64 * 128;
#pragma unroll
    for (int i = 0; i < 8; ++i) {
      int j = t + i * 256;
      int kk = j >> 5, q = j & 31;
      *(float4*)&tile[kk][q * 4] = *(const float4*)(src + kk * 128 + q * 4);
    }
    __syncthreads();
    const int col = t >> 1, kg0 = (t & 1) * 4;
    unsigned short hi[32], lo[32];
#pragma unroll
    for (int kk = 0; kk < 32; ++kk) {
      float v = tile[kg0 * 8 + kk][col];
      unsigned short h = f2bf(v);
      hi[kk] = h;
      lo[kk] = f2bf(v - bf2f(h));
    }
#pragma unroll
    for (int i = 0; i < 4; ++i) {
      size_t off = (size_t)b * 8192 + (size_t)(kg0 + i) * 1024 + (size_t)col * 8;
      u16x8 vh, vl;
#pragma unroll
      for (int e = 0; e < 8; ++e) { vh[e] = hi[i * 8 + e]; vl[e] = lo[i * 8 + e]; }
      *(u16x8*)(th1 + off) = vh;
      *(u16x8*)(tl1 + off) = vl;
    }
  } else if (b < 32) {
    int tt = (b - 16) * 256 + t;
#pragma unroll
    for (int h = 0; h < 2; ++h) {
      int c = tt + h * 4096;
      int kt = c >> 12, rem = c & 4095;
      int kg = rem >> 9, col = rem & 511;
      int kbase = kt * 64 + kg * 8;
      u16x8 vh, vl;
#pragma unroll
      for (int e = 0; e < 8; ++e) {
        float v = W[(size_t)(kbase + e) * 512 + col];
        unsigned short hh = f2bf(v);
        vh[e] = hh;
        vl[e] = f2bf(v - bf2f(hh));
      }
      size_t off = ((size_t)(kt * 8 + kg) * 512 + col) * 8;
      *(u16x8*)(th2 + off) = vh;
      *(u16x8*)(tl2 + off) = vl;
    }
  } else {
    int bb = b - 32;
    int a = (bb >> 3) * 16 + (t >> 4);
    int c = (bb & 7) * 16 + (t & 15);
    const float* wa = W + (size_t)a * 512;
    const float* wb = W + (size_t)c * 512;
    float acc = 0.f;
#pragma unroll 4
    for (int o = 0; o < 512; o += 4) {
      float4 xx = *(const float4*)(wa + o);
      float4 yy = *(const float4*)(wb + o);
      acc += xx.x * yy.x + xx.y * yy.y + xx.z * yy.z + xx.w * yy.w;
    }
    M[a * 128 + c] = acc;
  }
}

// ---------------------------------------------------------------------------
// K1: p = squash(x @ Wp + bp), split-bf16 via 32x32x16 MFMA. (round-8 state)
// ---------------------------------------------------------------------------
#define K1BUF 20480   // shorts per buffer (40 KB)

__global__ __launch_bounds__(256) void caps_primary(
    const float* __restrict__ x, const unsigned short* __restrict__ bth,
    const unsigned short* __restrict__ btl, const float* __restrict__ bp,
    float* __restrict__ p_out)
{
  __shared__ unsigned short lds[2 * K1BUF];   // 80 KB
  const int tid  = threadIdx.x;
  const int lane = tid & 63;
  const int wn   = tid >> 6;       // 0..3 -> cols wn*32..+31
  const int lc   = lane & 31;
  const int hi   = lane >> 5;
  const int row0 = blockIdx.x * 32;

  const int rowA = tid & 31;       // A staging: (row=rowA, ks=kgA)
  const int kgA  = tid >> 5;       // 0..7
  const float* xrow = x + (size_t)(row0 + rowA) * 1024 + kgA * 8;

  f32x16 acc;
#pragma unroll
  for (int j = 0; j < 16; ++j) acc[j] = 0.f;

  float4 a0, a1;

#define A_LOAD(kt) do { const float* xp_ = xrow + (kt) * 64; \
    a0 = *(const float4*)(xp_); a1 = *(const float4*)(xp_ + 4); } while (0)

#define B_ISSUE(kt, bufi) do { \
    unsigned short* Bh_ = lds + (bufi) * K1BUF + 4096; \
    unsigned short* Bl_ = lds + (bufi) * K1BUF + 12288; \
    const unsigned short* gh_ = bth + ((size_t)(kt) * 1024 + tid) * 8; \
    const unsigned short* gl_ = btl + ((size_t)(kt) * 1024 + tid) * 8; \
    _Pragma("unroll") for (int c_ = 0; c_ < 4; ++c_) { \
      GLD16(gh_ + c_ * 2048, Bh_ + (c_ * 256 + tid) * 8); \
      GLD16(gl_ + c_ * 2048, Bl_ + (c_ * 256 + tid) * 8); \
    } } while (0)

#define A_WRITE(bufi) do { u16x8 h_, l_; cvt8pk(a0, a1, h_, l_); \
    unsigned short* A_ = lds + (bufi) * K1BUF; \
    *(u16x8*)(A_ + (kgA * 32 + rowA) * 8) = h_; \
    *(u16x8*)(A_ + 2048 + (kgA * 32 + rowA) * 8) = l_; } while (0)

#define COMPUTE(bufi) do { \
    const unsigned short* F = lds + (bufi) * K1BUF; \
    _Pragma("unroll") \
    for (int kk = 0; kk < 4; ++kk) { \
      const int ks = kk * 2 + hi; \
      bf16x8 ah  = *(const bf16x8*)(F + (ks * 32 + lc) * 8); \
      bf16x8 al  = *(const bf16x8*)(F + 2048 + (ks * 32 + lc) * 8); \
      bf16x8 bh  = *(const bf16x8*)(F + 4096  + (ks * 128 + wn * 32 + lc) * 8); \
      bf16x8 blo = *(const bf16x8*)(F + 12288 + (ks * 128 + wn * 32 + lc) * 8); \
      acc = MFMA32(ah, bh,  acc); \
      acc = MFMA32(ah, blo, acc); \
      acc = MFMA32(al, bh,  acc); \
    } } while (0)

  // prologue
  A_LOAD(0);
  B_ISSUE(0, 0);
  A_WRITE(0);
  __syncthreads();

#pragma unroll 2
  for (int kt = 0; kt < 16; ++kt) {
    const int cur = kt & 1;
    if (kt < 15) {
      A_LOAD(kt + 1);           // global->reg (A), issued first
      B_ISSUE(kt + 1, cur ^ 1); // global->LDS async (B)
    }
    COMPUTE(cur);
    if (kt < 15) A_WRITE(cur ^ 1);
    __syncthreads();
  }
#undef A_LOAD
#undef B_ISSUE
#undef A_WRITE
#undef COMPUTE

  // epilogue: bias + per-capsule squash.
  // C/D 32x32: col = wn*32 + lc, row = (r&3) + 8*(r>>2) + 4*hi.
  const int col = wn * 32 + lc;
  const float bpv = bp[col];
#pragma unroll
  for (int r = 0; r < 16; ++r) {
    const int row = (r & 3) + 8 * (r >> 2) + 4 * hi;
    float val = acc[r] + bpv;
    float sq = val * val;
    sq += __shfl_xor(sq, 1); sq += __shfl_xor(sq, 2);
    sq += __shfl_xor(sq, 4); sq += __shfl_xor(sq, 8);
    float sc = (sq / (1.f + sq)) / sqrtf(sq + 1e-8f);
    p_out[(size_t)(row0 + row) * 128 + col] = val * sc;
  }
}

// ---------------------------------------------------------------------------
// K2: Gram-based routing v3. 256 blocks x 256 thr, 64 rows/block, lane = row.
// G phase: wave w handles 9 static pairs; per pair 16 INDEPENDENT accumulators
// (ta[ii]) so all 64 broadcast M loads pipeline (no serialized chain).
// M read direct from global (64 KB, L1/L2-hot, wave-uniform addresses).
// Routing on wave 0 only (lane = row). Output: cs[row][8] = scale*c (no q).
// ---------------------------------------------------------------------------
__global__ __launch_bounds__(256) void caps_route_g(
    const float* __restrict__ p_in, const float* __restrict__ Mg,
    float* __restrict__ cs_out)
{
  __shared__ float p_lds[128 * 67];   // [k][row] transposed, stride 67: 33.5 KB
  __shared__ float G_lds[36 * 65];    // [pair][row], stride 65: 9.1 KB
  const int tid  = threadIdx.x;
  const int lane = tid & 63;
  const int w    = tid >> 6;
  const int row0 = blockIdx.x * 64;

  // stage p transposed (global-coalesced reads)
#pragma unroll
  for (int i = 0; i < 8; ++i) {
    int j = tid + i * 256;
    int r = j >> 5, c4 = j & 31;
    f32x4 v = *(const f32x4*)(p_in + (size_t)(row0 + r) * 128 + c4 * 4);
    p_lds[(c4 * 4 + 0) * 67 + r] = v[0];
    p_lds[(c4 * 4 + 1) * 67 + r] = v[1];
    p_lds[(c4 * 4 + 2) * 67 + r] = v[2];
    p_lds[(c4 * 4 + 3) * 67 + r] = v[3];
  }
  __syncthreads();

#define DOPAIR(nn, mm) do { \
    float pn_[16], pm_[16]; \
    _Pragma("unroll") for (int j = 0; j < 16; ++j) { \
      pn_[j] = p_lds[((nn) * 16 + j) * 67 + lane]; \
      pm_[j] = p_lds[((mm) * 16 + j) * 67 + lane]; } \
    float ta_[16]; \
    _Pragma("unroll") for (int ii = 0; ii < 16; ++ii) ta_[ii] = 0.f; \
    _Pragma("unroll") for (int j4 = 0; j4 < 4; ++j4) { \
      _Pragma("unroll") for (int ii = 0; ii < 16; ++ii) { \
        f32x4 mv = *(const f32x4*)(Mg + ((nn) * 16 + ii) * 128 + (mm) * 16 + j4 * 4); \
        ta_[ii] = fmaf(mv[0], pm_[j4 * 4 + 0], ta_[ii]); \
        ta_[ii] = fmaf(mv[1], pm_[j4 * 4 + 1], ta_[ii]); \
        ta_[ii] = fmaf(mv[2], pm_[j4 * 4 + 2], ta_[ii]); \
        ta_[ii] = fmaf(mv[3], pm_[j4 * 4 + 3], ta_[ii]); } } \
    float g_ = 0.f; \
    _Pragma("unroll") for (int ii = 0; ii < 16; ++ii) g_ = fmaf(pn_[ii], ta_[ii], g_); \
    G_lds[gidx(nn, mm) * 65 + lane] = g_; } while (0)

  if (w == 0) {
    DOPAIR(0,0); DOPAIR(0,1); DOPAIR(0,2); DOPAIR(0,3); DOPAIR(0,4);
    DOPAIR(0,5); DOPAIR(0,6); DOPAIR(0,7); DOPAIR(1,1);
  } else if (w == 1) {
    DOPAIR(1,2); DOPAIR(1,3); DOPAIR(1,4); DOPAIR(1,5); DOPAIR(1,6);
    DOPAIR(1,7); DOPAIR(2,2); DOPAIR(2,3); DOPAIR(2,4);
  } else if (w == 2) {
    DOPAIR(2,5); DOPAIR(2,6); DOPAIR(2,7); DOPAIR(3,3); DOPAIR(3,4);
    DOPAIR(3,5); DOPAIR(3,6); DOPAIR(3,7); DOPAIR(4,4);
  } else {
    DOPAIR(4,5); DOPAIR(4,6); DOPAIR(4,7); DOPAIR(5,5); DOPAIR(5,6);
    DOPAIR(5,7); DOPAIR(6,6); DOPAIR(6,7); DOPAIR(7,7);
  }
#undef DOPAIR
  __syncthreads();

  // routing: wave 0, lane = row
  if (w == 0) {
    float Gf[36];
#pragma unroll
    for (int j = 0; j < 36; ++j) Gf[j] = G_lds[j * 65 + lane];
    float bb[8] = {0.f, 0.f, 0.f, 0.f, 0.f, 0.f, 0.f, 0.f};
    float cs[8];
#pragma unroll
    for (int it = 0; it < 3; ++it) {
      float mx = bb[0];
#pragma unroll
      for (int n = 1; n < 8; ++n) mx = fmaxf(mx, bb[n]);
      float e[8], Z = 0.f;
#pragma unroll
      for (int n = 0; n < 8; ++n) { e[n] = expf(bb[n] - mx); Z += e[n]; }
      float inv = 1.f / Z;
      float c[8];
#pragma unroll
      for (int n = 0; n < 8; ++n) c[n] = e[n] * inv;
      float t[8] = {0.f, 0.f, 0.f, 0.f, 0.f, 0.f, 0.f, 0.f};
#pragma unroll
      for (int n = 0; n < 8; ++n)
#pragma unroll
        for (int m = 0; m < 8; ++m)
          t[n] = fmaf(Gf[gidx(n, m)], c[m], t[n]);
      float ss = 0.f;
#pragma unroll
      for (int n = 0; n < 8; ++n) ss = fmaf(c[n], t[n], ss);
      float scale = (ss / (1.f + ss)) / sqrtf(ss + 1e-8f);
      if (it < 2) {
#pragma unroll
        for (int n = 0; n < 8; ++n) bb[n] += scale * t[n];
      } else {
#pragma unroll
        for (int n = 0; n < 8; ++n) cs[n] = scale * c[n];
      }
    }
    f32x4 c0 = {cs[0], cs[1], cs[2], cs[3]};
    f32x4 c1 = {cs[4], cs[5], cs[6], cs[7]};
    *(f32x4*)(cs_out + (size_t)(row0 + lane) * 8)     = c0;
    *(f32x4*)(cs_out + (size_t)(row0 + lane) * 8 + 4) = c1;
  }
}

// ---------------------------------------------------------------------------
// K3: v = (cs.p) @ Wflat  [16384,128]x[128,512] split-bf16 via 32x32x16 MFMA.
// cs folded into A-fragment load (q never materialized).
// ---------------------------------------------------------------------------
__global__ __launch_bounds__(512) void caps_vout(
    const float* __restrict__ p, const unsigned short* __restrict__ bth,
    const unsigned short* __restrict__ btl, const float* __restrict__ cs,
    float* __restrict__ out)
{
  __shared__ unsigned short Bsh[32768];   // hi @0, lo @16384 (ushorts)
  const int tid  = threadIdx.x;
  const int lane = tid & 63;
  const int w    = tid >> 6;
  const int wm   = w >> 2;         // 0..1 -> rows wm*32..+31
  const int wn   = w & 3;          // 0..3 -> cols wn*32..+31
  const int lc   = lane & 31;
  const int hi   = lane >> 5;
  const int row0 = blockIdx.x * 64;
  const int col0 = blockIdx.y * 128;

#pragma unroll
  for (int i = 0; i < 4; ++i) {
    int idx = tid + i * 512;               // 2048 chunks
    int kt = idx >> 10, kg = (idx >> 7) & 7, col = idx & 127;
    size_t g = ((size_t)(kt * 8 + kg) * 512 + col0 + col) * 8;
    *(u16x8*)&Bsh[idx * 8] = *(const u16x8*)(bth + g);
    *(u16x8*)&Bsh[16384 + idx * 8] = *(const u16x8*)(btl + g);
  }

  const int rA = row0 + wm * 32 + lc;
  const float* qp = p + (size_t)rA * 128;
  float cs8[8];
  *(f32x4*)&cs8[0] = *(const f32x4*)(cs + (size_t)rA * 8);
  *(f32x4*)&cs8[4] = *(const f32x4*)(cs + (size_t)rA * 8 + 4);
  __syncthreads();

  f32x16 acc;
#pragma unroll
  for (int j = 0; j < 16; ++j) acc[j] = 0.f;

#pragma unroll
  for (int kt = 0; kt < 2; ++kt) {
#pragma unroll
    for (int kk = 0; kk < 4; ++kk) {
      const float* qk = qp + kt * 64 + kk * 16 + hi * 8;
      float4 a0 = *(const float4*)(qk);
      float4 a1 = *(const float4*)(qk + 4);
      const float cv = cs8[kt * 4 + kk];   // capsule n = k/16 (hi*8+e < 16)
      a0.x *= cv; a0.y *= cv; a0.z *= cv; a0.w *= cv;
      a1.x *= cv; a1.y *= cv; a1.z *= cv; a1.w *= cv;
      bf16x8 ah, al;
      cvt8b(a0, a1, ah, al);
      const int ks = kk * 2 + hi;
      const int fi = ((kt * 8 + ks) * 128 + wn * 32 + lc) * 8;
      bf16x8 bh  = *(const bf16x8*)&Bsh[fi];
      bf16x8 blo = *(const bf16x8*)&Bsh[16384 + fi];
      acc = MFMA32(ah, bh,  acc);
      acc = MFMA32(ah, blo, acc);
      acc = MFMA32(al, bh,  acc);
    }
  }

#pragma unroll
  for (int r = 0; r < 16; ++r) {
    const int row = (r & 3) + 8 * (r >> 2) + 4 * hi;
    out[(size_t)(row0 + wm * 32 + row) * 512 + col0 + wn * 32 + lc] = acc[r];
  }
}

extern "C" void kernel_launch(void* const* d_in, const int* in_sizes, int n_in,
                              void* d_out, int out_size, void* d_ws, size_t ws_size,
                              hipStream_t stream) {
  (void)in_sizes; (void)n_in; (void)out_size; (void)ws_size;
  const float* x  = (const float*)d_in[0];
  const float* Wp = (const float*)d_in[1];
  const float* bp = (const float*)d_in[2];
  const float* W  = (const float*)d_in[3];
  // d_in[4] = n_routing (fixed = 3)
  char* ws = (char*)d_ws;
  float* p_ws = (float*)ws;                                   // 8 MB
  unsigned short* th1 = (unsigned short*)(ws + 8388608);      // 256 KB
  unsigned short* tl1 = (unsigned short*)(ws + 8650752);      // 256 KB
  unsigned short* th2 = (unsigned short*)(ws + 8912896);      // 128 KB
  unsigned short* tl2 = (unsigned short*)(ws + 9043968);      // 128 KB
  float* Mws = (float*)(ws + 9175040);                        // 64 KB
  float* cs_ws = (float*)(ws + 9240576);                      // 512 KB
  float* outp = (float*)d_out;

  caps_prep_all<<<96, 256, 0, stream>>>(Wp, W, th1, tl1, th2, tl2, Mws);
  caps_primary<<<512, 256, 0, stream>>>(x, th1, tl1, bp, p_ws);
  caps_route_g<<<256, 256, 0, stream>>>(p_ws, Mws, cs_ws);
  caps_vout<<<dim3(256, 4), 512, 0, stream>>>(p_ws, th2, tl2, cs_ws, outp);
}

// Round 11
// 84.262 us; speedup vs baseline: 2.3875x; 1.5565x over previous
//
#include <hip/hip_runtime.h>
#include <hip/hip_bf16.h>
#include <math.h>

typedef __attribute__((ext_vector_type(8))) short bf16x8;
typedef __attribute__((ext_vector_type(8))) unsigned short u16x8;
typedef __attribute__((ext_vector_type(4))) float f32x4;
typedef __attribute__((ext_vector_type(16))) float f32x16;

__device__ __forceinline__ unsigned short f2bf(float f) {
  unsigned u = __float_as_uint(f);
  return (unsigned short)((u + 0x7FFFu + ((u >> 16) & 1u)) >> 16);
}
__device__ __forceinline__ float bf2f(unsigned short h) {
  return __uint_as_float(((unsigned)h) << 16);
}
// fp32x8 -> bf16 hi/lo split via packed cvt (compiler emits v_cvt_pk_bf16_f32)
__device__ __forceinline__ void cvt8pk_a(const float* f, u16x8& h, u16x8& l) {
  unsigned* hp = (unsigned*)&h;
  unsigned* lp = (unsigned*)&l;
#pragma unroll
  for (int i = 0; i < 4; ++i) {
    __hip_bfloat162 hb = __float22bfloat162_rn(make_float2(f[2*i], f[2*i+1]));
    unsigned hv = *(unsigned*)&hb;
    hp[i] = hv;
    float r0 = f[2*i]     - __uint_as_float(hv << 16);
    float r1 = f[2*i + 1] - __uint_as_float(hv & 0xFFFF0000u);
    __hip_bfloat162 lb = __float22bfloat162_rn(make_float2(r0, r1));
    lp[i] = *(unsigned*)&lb;
  }
}
__device__ __forceinline__ void cvt8pk(const float4& a, const float4& b,
                                       u16x8& h, u16x8& l) {
  float f[8] = {a.x, a.y, a.z, a.w, b.x, b.y, b.z, b.w};
  cvt8pk_a(f, h, l);
}
__device__ __forceinline__ void cvt8b(const float4& a, const float4& b,
                                      bf16x8& h, bf16x8& l) {
  u16x8 hh, ll;
  cvt8pk(a, b, hh, ll);
  h = *(bf16x8*)&hh;
  l = *(bf16x8*)&ll;
}

#define GLD16(g, l) __builtin_amdgcn_global_load_lds( \
    (const __attribute__((address_space(1))) void*)(g), \
    (__attribute__((address_space(3))) void*)(l), 16, 0, 0)

#define MFMA32(a, b, c) __builtin_amdgcn_mfma_f32_32x32x16_bf16(a, b, c, 0, 0, 0)

// ---------------------------------------------------------------------------
// K0 (merged): blocks 0-15: split/transpose Wp -> th1/tl1 [kt16][ks8][col128][e8]
//              blocks 16-31: split Wflat -> th2/tl2 [kt2][ks8][col512][e8]
//              blocks 32-95: Gram M[a][c] = Wf[a]·Wf[c], written DIRECTLY in
//                            split-bf16 fragment layout [ks16][col128][e8]
// ---------------------------------------------------------------------------
__global__ __launch_bounds__(256) void caps_prep_all(
    const float* __restrict__ Wp, const float* __restrict__ W,
    unsigned short* __restrict__ th1, unsigned short* __restrict__ tl1,
    unsigned short* __restrict__ th2, unsigned short* __restrict__ tl2,
    unsigned short* __restrict__ th3, unsigned short* __restrict__ tl3)
{
  __shared__ float tile[64][128];
  const int t = threadIdx.x, b = blockIdx.x;
  if (b < 16) {
    const float* src = Wp + (size_t)b * 64 * 128;
#pragma unroll
    for (int i = 0; i < 8; ++i) {
      int j = t + i * 256;
      int kk = j >> 5, q = j & 31;
      *(float4*)&tile[kk][q * 4] = *(const float4*)(src + kk * 128 + q * 4);
    }
    __syncthreads();
    const int col = t >> 1, kg0 = (t & 1) * 4;
    unsigned short hi[32], lo[32];
#pragma unroll
    for (int kk = 0; kk < 32; ++kk) {
      float v = tile[kg0 * 8 + kk][col];
      unsigned short h = f2bf(v);
      hi[kk] = h;
      lo[kk] = f2bf(v - bf2f(h));
    }
#pragma unroll
    for (int i = 0; i < 4; ++i) {
      size_t off = (size_t)b * 8192 + (size_t)(kg0 + i) * 1024 + (size_t)col * 8;
      u16x8 vh, vl;
#pragma unroll
      for (int e = 0; e < 8; ++e) { vh[e] = hi[i * 8 + e]; vl[e] = lo[i * 8 + e]; }
      *(u16x8*)(th1 + off) = vh;
      *(u16x8*)(tl1 + off) = vl;
    }
  } else if (b < 32) {
    int tt = (b - 16) * 256 + t;
#pragma unroll
    for (int h = 0; h < 2; ++h) {
      int c = tt + h * 4096;
      int kt = c >> 12, rem = c & 4095;
      int kg = rem >> 9, col = rem & 511;
      int kbase = kt * 64 + kg * 8;
      u16x8 vh, vl;
#pragma unroll
      for (int e = 0; e < 8; ++e) {
        float v = W[(size_t)(kbase + e) * 512 + col];
        unsigned short hh = f2bf(v);
        vh[e] = hh;
        vl[e] = f2bf(v - bf2f(hh));
      }
      size_t off = ((size_t)(kt * 8 + kg) * 512 + col) * 8;
      *(u16x8*)(th2 + off) = vh;
      *(u16x8*)(tl2 + off) = vl;
    }
  } else {
    int bb = b - 32;
    int a = (bb >> 3) * 16 + (t >> 4);
    int c = (bb & 7) * 16 + (t & 15);
    const float* wa = W + (size_t)a * 512;
    const float* wb = W + (size_t)c * 512;
    float acc = 0.f;
#pragma unroll 4
    for (int o = 0; o < 512; o += 4) {
      float4 xx = *(const float4*)(wa + o);
      float4 yy = *(const float4*)(wb + o);
      acc += xx.x * yy.x + xx.y * yy.y + xx.z * yy.z + xx.w * yy.w;
    }
    unsigned short h = f2bf(acc);
    unsigned short l = f2bf(acc - bf2f(h));
    size_t off = ((size_t)(a >> 3) * 128 + c) * 8 + (a & 7);
    th3[off] = h;
    tl3[off] = l;
  }
}

// ---------------------------------------------------------------------------
// K1: p = squash(x @ Wp + bp), split-bf16 via 32x32x16 MFMA. (round-8 state)
// ---------------------------------------------------------------------------
#define K1BUF 20480   // shorts per buffer (40 KB)

__global__ __launch_bounds__(256) void caps_primary(
    const float* __restrict__ x, const unsigned short* __restrict__ bth,
    const unsigned short* __restrict__ btl, const float* __restrict__ bp,
    float* __restrict__ p_out)
{
  __shared__ unsigned short lds[2 * K1BUF];   // 80 KB
  const int tid  = threadIdx.x;
  const int lane = tid & 63;
  const int wn   = tid >> 6;       // 0..3 -> cols wn*32..+31
  const int lc   = lane & 31;
  const int hi   = lane >> 5;
  const int row0 = blockIdx.x * 32;

  const int rowA = tid & 31;       // A staging: (row=rowA, ks=kgA)
  const int kgA  = tid >> 5;       // 0..7
  const float* xrow = x + (size_t)(row0 + rowA) * 1024 + kgA * 8;

  f32x16 acc;
#pragma unroll
  for (int j = 0; j < 16; ++j) acc[j] = 0.f;

  float4 a0, a1;

#define A_LOAD(kt) do { const float* xp_ = xrow + (kt) * 64; \
    a0 = *(const float4*)(xp_); a1 = *(const float4*)(xp_ + 4); } while (0)

#define B_ISSUE(kt, bufi) do { \
    unsigned short* Bh_ = lds + (bufi) * K1BUF + 4096; \
    unsigned short* Bl_ = lds + (bufi) * K1BUF + 12288; \
    const unsigned short* gh_ = bth + ((size_t)(kt) * 1024 + tid) * 8; \
    const unsigned short* gl_ = btl + ((size_t)(kt) * 1024 + tid) * 8; \
    _Pragma("unroll") for (int c_ = 0; c_ < 4; ++c_) { \
      GLD16(gh_ + c_ * 2048, Bh_ + (c_ * 256 + tid) * 8); \
      GLD16(gl_ + c_ * 2048, Bl_ + (c_ * 256 + tid) * 8); \
    } } while (0)

#define A_WRITE(bufi) do { u16x8 h_, l_; cvt8pk(a0, a1, h_, l_); \
    unsigned short* A_ = lds + (bufi) * K1BUF; \
    *(u16x8*)(A_ + (kgA * 32 + rowA) * 8) = h_; \
    *(u16x8*)(A_ + 2048 + (kgA * 32 + rowA) * 8) = l_; } while (0)

#define COMPUTE(bufi) do { \
    const unsigned short* F = lds + (bufi) * K1BUF; \
    _Pragma("unroll") \
    for (int kk = 0; kk < 4; ++kk) { \
      const int ks = kk * 2 + hi; \
      bf16x8 ah  = *(const bf16x8*)(F + (ks * 32 + lc) * 8); \
      bf16x8 al  = *(const bf16x8*)(F + 2048 + (ks * 32 + lc) * 8); \
      bf16x8 bh  = *(const bf16x8*)(F + 4096  + (ks * 128 + wn * 32 + lc) * 8); \
      bf16x8 blo = *(const bf16x8*)(F + 12288 + (ks * 128 + wn * 32 + lc) * 8); \
      acc = MFMA32(ah, bh,  acc); \
      acc = MFMA32(ah, blo, acc); \
      acc = MFMA32(al, bh,  acc); \
    } } while (0)

  // prologue
  A_LOAD(0);
  B_ISSUE(0, 0);
  A_WRITE(0);
  __syncthreads();

#pragma unroll 2
  for (int kt = 0; kt < 16; ++kt) {
    const int cur = kt & 1;
    if (kt < 15) {
      A_LOAD(kt + 1);           // global->reg (A), issued first
      B_ISSUE(kt + 1, cur ^ 1); // global->LDS async (B)
    }
    COMPUTE(cur);
    if (kt < 15) A_WRITE(cur ^ 1);
    __syncthreads();
  }
#undef A_LOAD
#undef B_ISSUE
#undef A_WRITE
#undef COMPUTE

  // epilogue: bias + per-capsule squash.
  // C/D 32x32: col = wn*32 + lc, row = (r&3) + 8*(r>>2) + 4*hi.
  const int col = wn * 32 + lc;
  const float bpv = bp[col];
#pragma unroll
  for (int r = 0; r < 16; ++r) {
    const int row = (r & 3) + 8 * (r >> 2) + 4 * hi;
    float val = acc[r] + bpv;
    float sq = val * val;
    sq += __shfl_xor(sq, 1); sq += __shfl_xor(sq, 2);
    sq += __shfl_xor(sq, 4); sq += __shfl_xor(sq, 8);
    float sc = (sq / (1.f + sq)) / sqrtf(sq + 1e-8f);
    p_out[(size_t)(row0 + row) * 128 + col] = val * sc;
  }
}

// ---------------------------------------------------------------------------
// K2: routing as 3 fused MFMA passes. 256 blocks x 512 thr (8 waves, 2/SIMD),
// 64 rows/block. Per iteration: Y = (c o p) @ M (split-bf16 32x32x16 MFMA,
// wave (wm,wn) owns 32x32 tile), t[n] = seg-dot(p_n, Y_n) via 16-lane shuffle,
// softmax/scale state updated by wave 0 (lane = row). Emits cs = scale*c.
// ---------------------------------------------------------------------------
__global__ __launch_bounds__(512) void caps_route_g(
    const float* __restrict__ p_in, const unsigned short* __restrict__ mh,
    const unsigned short* __restrict__ ml, float* __restrict__ cs_out)
{
  __shared__ float pT[128 * 65];          // [k][row], 33.3 KB, conflict-free reads
  __shared__ unsigned short Msh[32768];   // M split: hi @0, lo @16384
  __shared__ float t_lds[64 * 9];
  __shared__ float c_lds[64 * 9];
  const int tid  = threadIdx.x;
  const int lane = tid & 63;
  const int w    = tid >> 6;
  const int wm   = w >> 2;         // 0..1 -> rows wm*32..+31
  const int wn   = w & 3;          // 0..3 -> cols wn*32..+31
  const int lc   = lane & 31;
  const int hi   = lane >> 5;
  const int row0 = blockIdx.x * 64;

  // stage M (coalesced u16x8, linear layout preserved)
#pragma unroll
  for (int i = 0; i < 4; ++i) {
    int idx = tid + i * 512;   // 2048 chunks
    *(u16x8*)&Msh[idx * 8] = *(const u16x8*)(mh + (size_t)idx * 8);
    *(u16x8*)&Msh[16384 + idx * 8] = *(const u16x8*)(ml + (size_t)idx * 8);
  }
  // stage p transposed (coalesced global reads; scalar LDS scatter)
#pragma unroll
  for (int i = 0; i < 4; ++i) {
    int j = tid + i * 512;
    int r = j >> 5, c4 = j & 31;
    f32x4 v = *(const f32x4*)(p_in + (size_t)(row0 + r) * 128 + c4 * 4);
    pT[(c4 * 4 + 0) * 65 + r] = v[0];
    pT[(c4 * 4 + 1) * 65 + r] = v[1];
    pT[(c4 * 4 + 2) * 65 + r] = v[2];
    pT[(c4 * 4 + 3) * 65 + r] = v[3];
  }
  if (w == 0) {
#pragma unroll
    for (int n = 0; n < 8; ++n) c_lds[lane * 9 + n] = 0.125f;
  }
  __syncthreads();

  const int arow = wm * 32 + lc;   // A row for this lane
  const int col  = wn * 32 + lc;   // output col for this lane
  const int cap  = wn * 2 + (lc >> 4);
  float bb[8] = {0.f, 0.f, 0.f, 0.f, 0.f, 0.f, 0.f, 0.f};   // wave-0 state

#pragma unroll 1
  for (int it = 0; it < 3; ++it) {
    f32x16 acc;
#pragma unroll
    for (int j = 0; j < 16; ++j) acc[j] = 0.f;

    // Y = (c o p) @ M : 8 k-steps, capsule n == k-step kk
#pragma unroll
    for (int kk = 0; kk < 8; ++kk) {
      const float cv = c_lds[arow * 9 + kk];
      float q[8];
#pragma unroll
      for (int e = 0; e < 8; ++e)
        q[e] = pT[(kk * 16 + hi * 8 + e) * 65 + arow] * cv;
      u16x8 hq, lq;
      cvt8pk_a(q, hq, lq);
      const int fi = ((kk * 2 + hi) * 128 + col) * 8;
      bf16x8 mbh = *(const bf16x8*)&Msh[fi];
      bf16x8 mbl = *(const bf16x8*)&Msh[16384 + fi];
      acc = MFMA32(*(bf16x8*)&hq, mbh, acc);
      acc = MFMA32(*(bf16x8*)&hq, mbl, acc);
      acc = MFMA32(*(bf16x8*)&lq, mbh, acc);
    }

    // t partials: per r, prod = p[row][col] * Y[row][col], reduce 16 lanes
    float tp[16];
#pragma unroll
    for (int r = 0; r < 16; ++r) {
      const int row = wm * 32 + (r & 3) + 8 * (r >> 2) + 4 * hi;
      float prod = pT[col * 65 + row] * acc[r];
      prod += __shfl_xor(prod, 1);
      prod += __shfl_xor(prod, 2);
      prod += __shfl_xor(prod, 4);
      prod += __shfl_xor(prod, 8);
      tp[r] = prod;
    }
    __syncthreads();                 // wave0's previous t-read done
    if ((lc & 15) == 0) {
#pragma unroll
      for (int r = 0; r < 16; ++r) {
        const int row = wm * 32 + (r & 3) + 8 * (r >> 2) + 4 * hi;
        t_lds[row * 9 + cap] = tp[r];
      }
    }
    __syncthreads();

    if (w == 0) {
      float c[8], t[8];
#pragma unroll
      for (int n = 0; n < 8; ++n) {
        c[n] = c_lds[lane * 9 + n];
        t[n] = t_lds[lane * 9 + n];
      }
      float ss = 0.f;
#pragma unroll
      for (int n = 0; n < 8; ++n) ss = fmaf(c[n], t[n], ss);
      float scale = (ss / (1.f + ss)) / sqrtf(ss + 1e-8f);
      if (it < 2) {
#pragma unroll
        for (int n = 0; n < 8; ++n) bb[n] += scale * t[n];
        float mx = bb[0];
#pragma unroll
        for (int n = 1; n < 8; ++n) mx = fmaxf(mx, bb[n]);
        float e[8], Z = 0.f;
#pragma unroll
        for (int n = 0; n < 8; ++n) { e[n] = expf(bb[n] - mx); Z += e[n]; }
        float inv = 1.f / Z;
#pragma unroll
        for (int n = 0; n < 8; ++n) c_lds[lane * 9 + n] = e[n] * inv;
      } else {
        f32x4 c0 = {scale * c[0], scale * c[1], scale * c[2], scale * c[3]};
        f32x4 c1 = {scale * c[4], scale * c[5], scale * c[6], scale * c[7]};
        *(f32x4*)(cs_out + (size_t)(row0 + lane) * 8)     = c0;
        *(f32x4*)(cs_out + (size_t)(row0 + lane) * 8 + 4) = c1;
      }
    }
    __syncthreads();
  }
}

// ---------------------------------------------------------------------------
// K3: v = (cs.p) @ Wflat  [16384,128]x[128,512] split-bf16 via 32x32x16 MFMA.
// cs folded into A-fragment load (q never materialized). (verified round 10)
// ---------------------------------------------------------------------------
__global__ __launch_bounds__(512) void caps_vout(
    const float* __restrict__ p, const unsigned short* __restrict__ bth,
    const unsigned short* __restrict__ btl, const float* __restrict__ cs,
    float* __restrict__ out)
{
  __shared__ unsigned short Bsh[32768];   // hi @0, lo @16384 (ushorts)
  const int tid  = threadIdx.x;
  const int lane = tid & 63;
  const int w    = tid >> 6;
  const int wm   = w >> 2;         // 0..1 -> rows wm*32..+31
  const int wn   = w & 3;          // 0..3 -> cols wn*32..+31
  const int lc   = lane & 31;
  const int hi   = lane >> 5;
  const int row0 = blockIdx.x * 64;
  const int col0 = blockIdx.y * 128;

#pragma unroll
  for (int i = 0; i < 4; ++i) {
    int idx = tid + i * 512;               // 2048 chunks
    int kt = idx >> 10, kg = (idx >> 7) & 7, col = idx & 127;
    size_t g = ((size_t)(kt * 8 + kg) * 512 + col0 + col) * 8;
    *(u16x8*)&Bsh[idx * 8] = *(const u16x8*)(bth + g);
    *(u16x8*)&Bsh[16384 + idx * 8] = *(const u16x8*)(btl + g);
  }

  const int rA = row0 + wm * 32 + lc;
  const float* qp = p + (size_t)rA * 128;
  float cs8[8];
  *(f32x4*)&cs8[0] = *(const f32x4*)(cs + (size_t)rA * 8);
  *(f32x4*)&cs8[4] = *(const f32x4*)(cs + (size_t)rA * 8 + 4);
  __syncthreads();

  f32x16 acc;
#pragma unroll
  for (int j = 0; j < 16; ++j) acc[j] = 0.f;

#pragma unroll
  for (int kt = 0; kt < 2; ++kt) {
#pragma unroll
    for (int kk = 0; kk < 4; ++kk) {
      const float* qk = qp + kt * 64 + kk * 16 + hi * 8;
      float4 a0 = *(const float4*)(qk);
      float4 a1 = *(const float4*)(qk + 4);
      const float cv = cs8[kt * 4 + kk];   // capsule n = k/16
      a0.x *= cv; a0.y *= cv; a0.z *= cv; a0.w *= cv;
      a1.x *= cv; a1.y *= cv; a1.z *= cv; a1.w *= cv;
      bf16x8 ah, al;
      cvt8b(a0, a1, ah, al);
      const int ks = kk * 2 + hi;
      const int fi = ((kt * 8 + ks) * 128 + wn * 32 + lc) * 8;
      bf16x8 bh  = *(const bf16x8*)&Bsh[fi];
      bf16x8 blo = *(const bf16x8*)&Bsh[16384 + fi];
      acc = MFMA32(ah, bh,  acc);
      acc = MFMA32(ah, blo, acc);
      acc = MFMA32(al, bh,  acc);
    }
  }

#pragma unroll
  for (int r = 0; r < 16; ++r) {
    const int row = (r & 3) + 8 * (r >> 2) + 4 * hi;
    out[(size_t)(row0 + wm * 32 + row) * 512 + col0 + wn * 32 + lc] = acc[r];
  }
}

extern "C" void kernel_launch(void* const* d_in, const int* in_sizes, int n_in,
                              void* d_out, int out_size, void* d_ws, size_t ws_size,
                              hipStream_t stream) {
  (void)in_sizes; (void)n_in; (void)out_size; (void)ws_size;
  const float* x  = (const float*)d_in[0];
  const float* Wp = (const float*)d_in[1];
  const float* bp = (const float*)d_in[2];
  const float* W  = (const float*)d_in[3];
  // d_in[4] = n_routing (fixed = 3)
  char* ws = (char*)d_ws;
  float* p_ws = (float*)ws;                                   // 8 MB
  unsigned short* th1 = (unsigned short*)(ws + 8388608);      // 256 KB
  unsigned short* tl1 = (unsigned short*)(ws + 8650752);      // 256 KB
  unsigned short* th2 = (unsigned short*)(ws + 8912896);      // 128 KB
  unsigned short* tl2 = (unsigned short*)(ws + 9043968);      // 128 KB
  unsigned short* th3 = (unsigned short*)(ws + 9175040);      // 32 KB (M hi)
  unsigned short* tl3 = (unsigned short*)(ws + 9207808);      // 32 KB (M lo)
  float* cs_ws = (float*)(ws + 9240576);                      // 512 KB
  float* outp = (float*)d_out;

  caps_prep_all<<<96, 256, 0, stream>>>(Wp, W, th1, tl1, th2, tl2, th3, tl3);
  caps_primary<<<512, 256, 0, stream>>>(x, th1, tl1, bp, p_ws);
  caps_route_g<<<256, 512, 0, stream>>>(p_ws, th3, tl3, cs_ws);
  caps_vout<<<dim3(256, 4), 512, 0, stream>>>(p_ws, th2, tl2, cs_ws, outp);
}